// Round 4
// baseline (30.386 us; speedup 1.0000x reference)
//
#include <hip/hip_runtime.h>

// Fused 4D max pool, K=2 S=2 P=0 over (T,D,H,W) of [B=2,C=16,T=32,D=32,H=32,W=32] f32.
// Output [2,16,16,16,16,16] f32.
//
// Round 4: round-2 structure (4 outputs/thread, 16x16B loads, 16B store) with
// nontemporal hints via clang native ext_vector float4 (HIP_vector_type is a
// struct — the builtin rejects it).

typedef float f32x4 __attribute__((ext_vector_type(4)));

#define IT   32
#define ID   32
#define IH   32          // input rows of 8 f32x4 (32 floats = 128 B)

__global__ __launch_bounds__(256) void maxpool4d_kernel(
    const f32x4* __restrict__ x4, f32x4* __restrict__ out4)
{
    int idx = blockIdx.x * blockDim.x + threadIdx.x;
    // idx = ((((bc*16 + ot)*16 + od)*16 + oh)*4 + owq)
    int owq = idx & 3;
    int oh  = (idx >> 2)  & 15;
    int od  = (idx >> 6)  & 15;
    int ot  = (idx >> 10) & 15;
    int bc  = idx >> 14;

    int t0 = ot << 1, d0 = od << 1, h0 = oh << 1;

    // input row index (rows of 8 f32x4): ((bc*IT + t)*ID + d)*IH + h
    int base = ((bc * IT + t0) * ID + d0) * IH + h0;

    f32x4 acc0, acc1;
    bool first = true;
    #pragma unroll
    for (int tt = 0; tt < 2; ++tt) {
        #pragma unroll
        for (int dd = 0; dd < 2; ++dd) {
            #pragma unroll
            for (int hh = 0; hh < 2; ++hh) {
                int row = base + ((tt * ID + dd) * IH + hh);
                const f32x4* p = &x4[row * 8 + owq * 2];
                f32x4 v0 = __builtin_nontemporal_load(p);
                f32x4 v1 = __builtin_nontemporal_load(p + 1);
                if (first) {
                    acc0 = v0; acc1 = v1; first = false;
                } else {
                    acc0.x = fmaxf(acc0.x, v0.x);
                    acc0.y = fmaxf(acc0.y, v0.y);
                    acc0.z = fmaxf(acc0.z, v0.z);
                    acc0.w = fmaxf(acc0.w, v0.w);
                    acc1.x = fmaxf(acc1.x, v1.x);
                    acc1.y = fmaxf(acc1.y, v1.y);
                    acc1.z = fmaxf(acc1.z, v1.z);
                    acc1.w = fmaxf(acc1.w, v1.w);
                }
            }
        }
    }

    f32x4 r;
    r.x = fmaxf(acc0.x, acc0.y);
    r.y = fmaxf(acc0.z, acc0.w);
    r.z = fmaxf(acc1.x, acc1.y);
    r.w = fmaxf(acc1.z, acc1.w);
    __builtin_nontemporal_store(r, &out4[idx]);
}

extern "C" void kernel_launch(void* const* d_in, const int* in_sizes, int n_in,
                              void* d_out, int out_size, void* d_ws, size_t ws_size,
                              hipStream_t stream)
{
    const f32x4* x4 = (const f32x4*)d_in[0];
    f32x4* out4 = (f32x4*)d_out;

    int n_threads = out_size / 4;               // 524,288
    int block = 256;
    int grid = (n_threads + block - 1) / block; // 2048

    maxpool4d_kernel<<<grid, block, 0, stream>>>(x4, out4);
}

// Round 5
// 25.293 us; speedup vs baseline: 1.2014x; 1.2014x over previous
//
#include <hip/hip_runtime.h>

// Fused 4D max pool, K=2 S=2 P=0 over (T,D,H,W) of [B=2,C=16,T=32,D=32,H=32,W=32] f32.
// Output [2,16,16,16,16,16] f32.
//
// Round 5: round-2 structure (4 outputs/thread, 16x16B cached loads, 16B store).
// NT hint on the STORE only — round 4 showed nt loads defeat L3 residency of
// the 128 MiB input (25.2 -> 30.4 us); output is write-once so nt store is safe.

typedef float f32x4 __attribute__((ext_vector_type(4)));

#define IT   32
#define ID   32
#define IH   32          // input rows of 8 f32x4 (32 floats = 128 B)

__global__ __launch_bounds__(256) void maxpool4d_kernel(
    const f32x4* __restrict__ x4, f32x4* __restrict__ out4)
{
    int idx = blockIdx.x * blockDim.x + threadIdx.x;
    // idx = ((((bc*16 + ot)*16 + od)*16 + oh)*4 + owq)
    int owq = idx & 3;
    int oh  = (idx >> 2)  & 15;
    int od  = (idx >> 6)  & 15;
    int ot  = (idx >> 10) & 15;
    int bc  = idx >> 14;

    int t0 = ot << 1, d0 = od << 1, h0 = oh << 1;

    // input row index (rows of 8 f32x4): ((bc*IT + t)*ID + d)*IH + h
    int base = ((bc * IT + t0) * ID + d0) * IH + h0;

    f32x4 acc0, acc1;
    bool first = true;
    #pragma unroll
    for (int tt = 0; tt < 2; ++tt) {
        #pragma unroll
        for (int dd = 0; dd < 2; ++dd) {
            #pragma unroll
            for (int hh = 0; hh < 2; ++hh) {
                int row = base + ((tt * ID + dd) * IH + hh);
                const f32x4* p = &x4[row * 8 + owq * 2];
                f32x4 v0 = p[0];
                f32x4 v1 = p[1];
                if (first) {
                    acc0 = v0; acc1 = v1; first = false;
                } else {
                    acc0.x = fmaxf(acc0.x, v0.x);
                    acc0.y = fmaxf(acc0.y, v0.y);
                    acc0.z = fmaxf(acc0.z, v0.z);
                    acc0.w = fmaxf(acc0.w, v0.w);
                    acc1.x = fmaxf(acc1.x, v1.x);
                    acc1.y = fmaxf(acc1.y, v1.y);
                    acc1.z = fmaxf(acc1.z, v1.z);
                    acc1.w = fmaxf(acc1.w, v1.w);
                }
            }
        }
    }

    f32x4 r;
    r.x = fmaxf(acc0.x, acc0.y);
    r.y = fmaxf(acc0.z, acc0.w);
    r.z = fmaxf(acc1.x, acc1.y);
    r.w = fmaxf(acc1.z, acc1.w);
    __builtin_nontemporal_store(r, &out4[idx]);
}

extern "C" void kernel_launch(void* const* d_in, const int* in_sizes, int n_in,
                              void* d_out, int out_size, void* d_ws, size_t ws_size,
                              hipStream_t stream)
{
    const f32x4* x4 = (const f32x4*)d_in[0];
    f32x4* out4 = (f32x4*)d_out;

    int n_threads = out_size / 4;               // 524,288
    int block = 256;
    int grid = (n_threads + block - 1) / block; // 2048

    maxpool4d_kernel<<<grid, block, 0, stream>>>(x4, out4);
}